// Round 1
// baseline (1043.925 us; speedup 1.0000x reference)
//
#include <hip/hip_runtime.h>

#define NN 50000
#define NE 800000
#define F  128
#define NB 2

// ---------------- CSR build ----------------

__global__ void count_kernel(const int* __restrict__ dst, int* __restrict__ cnt) {
    int e = blockIdx.x * blockDim.x + threadIdx.x;
    if (e < NE) atomicAdd(&cnt[dst[e]], 1);
}

__global__ void scan_kernel(const int* __restrict__ cnt, int* __restrict__ rowptr) {
    __shared__ int sd[1024];
    __shared__ int carry;
    if (threadIdx.x == 0) carry = 0;
    __syncthreads();
    for (int base = 0; base < NN; base += 1024) {
        int i = base + (int)threadIdx.x;
        int v = (i < NN) ? cnt[i] : 0;
        sd[threadIdx.x] = v;
        __syncthreads();
        for (int off = 1; off < 1024; off <<= 1) {
            int t = 0;
            if ((int)threadIdx.x >= off) t = sd[threadIdx.x - off];
            __syncthreads();
            sd[threadIdx.x] += t;
            __syncthreads();
        }
        if (i < NN) rowptr[i] = carry + sd[threadIdx.x] - v;  // exclusive
        __syncthreads();
        if (threadIdx.x == 0) carry += sd[1023];
        __syncthreads();
    }
    if (threadIdx.x == 0) rowptr[NN] = carry;
}

__global__ void deginv_kernel(const int* __restrict__ cnt, float* __restrict__ dinv) {
    int n = blockIdx.x * blockDim.x + threadIdx.x;
    if (n < NN) {
        int d = cnt[n];
        dinv[n] = (d > 0) ? 1.0f / (float)d : 0.0f;
    }
}

__global__ void fill_kernel(const int* __restrict__ src, const int* __restrict__ dst,
                            const int* __restrict__ rowptr, int* __restrict__ cursor,
                            int* __restrict__ eidx) {
    int e = blockIdx.x * blockDim.x + threadIdx.x;
    if (e < NE) {
        int d = dst[e];
        int p = rowptr[d] + atomicAdd(&cursor[d], 1);
        eidx[p] = src[e];
    }
}

// ---------------- mean aggregation: one wave per node ----------------

__global__ void aggregate_kernel(const float* __restrict__ h, const int* __restrict__ rowptr,
                                 const int* __restrict__ eidx, const float* __restrict__ dinv,
                                 float* __restrict__ agg) {
    int gtid = blockIdx.x * blockDim.x + threadIdx.x;
    int node = gtid >> 6;
    int lane = gtid & 63;
    if (node >= NN) return;
    int s0 = rowptr[node], s1 = rowptr[node + 1];
    float ax = 0.f, ay = 0.f;
    for (int e = s0; e < s1; ++e) {
        int s = eidx[e];
        float2 v = *reinterpret_cast<const float2*>(&h[(size_t)s * F + lane * 2]);
        ax += v.x;
        ay += v.y;
    }
    float di = dinv[node];
    float2 r;
    r.x = ax * di;
    r.y = ay * di;
    *reinterpret_cast<float2*>(&agg[(size_t)node * F + lane * 2]) = r;
}

// ---------------- fused SGEMM: out = relu([h|agg] @ [Wself|Wneigh]^T + b) ----------------
// BM=128 rows x BN=128 cols per block, BK=16, 256 threads, 8x8 per thread.

#define BM 128
#define BK 16

__global__ __launch_bounds__(256) void sage_gemm(
    const float* __restrict__ Hs, const float* __restrict__ Ha,
    const float* __restrict__ Wself, const float* __restrict__ Wneigh,
    const float* __restrict__ bias, float* __restrict__ out)
{
    __shared__ float Xs[BK][BM + 4];
    __shared__ float Wt[BK][BM + 4];

    int tid = threadIdx.x;
    int tm = tid >> 4;   // 0..15 -> row group of 8
    int tn = tid & 15;   // 0..15 -> col group of 8
    int M0 = blockIdx.x * BM;

    int lm = tid >> 2;         // 0..63
    int lk = (tid & 3) * 4;    // 0,4,8,12

    float acc[8][8];
#pragma unroll
    for (int i = 0; i < 8; ++i)
#pragma unroll
        for (int j = 0; j < 8; ++j) acc[i][j] = 0.f;

    for (int kk = 0; kk < 256; kk += BK) {
        const float* X = (kk < 128) ? Hs : Ha;
        const float* W = (kk < 128) ? Wself : Wneigh;
        int kl = kk & 127;

        // stage X tile transposed: Xs[k][m] = X[M0+m][kl+k]
#pragma unroll
        for (int hh = 0; hh < 2; ++hh) {
            int m = lm + hh * 64;
            int gm = M0 + m;
            float4 v = make_float4(0.f, 0.f, 0.f, 0.f);
            if (gm < NN) v = *reinterpret_cast<const float4*>(&X[(size_t)gm * F + kl + lk]);
            Xs[lk + 0][m] = v.x;
            Xs[lk + 1][m] = v.y;
            Xs[lk + 2][m] = v.z;
            Xs[lk + 3][m] = v.w;
        }
        // stage W tile transposed: Wt[k][j] = W[j][kl+k]
#pragma unroll
        for (int hh = 0; hh < 2; ++hh) {
            int j = lm + hh * 64;
            float4 v = *reinterpret_cast<const float4*>(&W[(size_t)j * F + kl + lk]);
            Wt[lk + 0][j] = v.x;
            Wt[lk + 1][j] = v.y;
            Wt[lk + 2][j] = v.z;
            Wt[lk + 3][j] = v.w;
        }
        __syncthreads();

#pragma unroll
        for (int k = 0; k < BK; ++k) {
            const float4* xa = reinterpret_cast<const float4*>(&Xs[k][tm * 8]);
            float4 a0 = xa[0], a1 = xa[1];
            const float4* wv = reinterpret_cast<const float4*>(&Wt[k][tn * 8]);
            float4 w0 = wv[0], w1 = wv[1];
            float a[8] = {a0.x, a0.y, a0.z, a0.w, a1.x, a1.y, a1.z, a1.w};
            float w[8] = {w0.x, w0.y, w0.z, w0.w, w1.x, w1.y, w1.z, w1.w};
#pragma unroll
            for (int i = 0; i < 8; ++i)
#pragma unroll
                for (int j = 0; j < 8; ++j)
                    acc[i][j] = fmaf(a[i], w[j], acc[i][j]);
        }
        __syncthreads();
    }

    // epilogue: bias + relu
    float4 bv0 = *reinterpret_cast<const float4*>(&bias[tn * 8]);
    float4 bv1 = *reinterpret_cast<const float4*>(&bias[tn * 8 + 4]);
    float bb[8] = {bv0.x, bv0.y, bv0.z, bv0.w, bv1.x, bv1.y, bv1.z, bv1.w};

#pragma unroll
    for (int i = 0; i < 8; ++i) {
        int gm = M0 + tm * 8 + i;
        if (gm < NN) {
            float4 r0, r1;
            r0.x = fmaxf(acc[i][0] + bb[0], 0.f);
            r0.y = fmaxf(acc[i][1] + bb[1], 0.f);
            r0.z = fmaxf(acc[i][2] + bb[2], 0.f);
            r0.w = fmaxf(acc[i][3] + bb[3], 0.f);
            r1.x = fmaxf(acc[i][4] + bb[4], 0.f);
            r1.y = fmaxf(acc[i][5] + bb[5], 0.f);
            r1.z = fmaxf(acc[i][6] + bb[6], 0.f);
            r1.w = fmaxf(acc[i][7] + bb[7], 0.f);
            float* op = &out[(size_t)gm * F + tn * 8];
            *reinterpret_cast<float4*>(op) = r0;
            *reinterpret_cast<float4*>(op + 4) = r1;
        }
    }
}

// ---------------- launcher ----------------

extern "C" void kernel_launch(void* const* d_in, const int* in_sizes, int n_in,
                              void* d_out, int out_size, void* d_ws, size_t ws_size,
                              hipStream_t stream) {
    const float* x  = (const float*)d_in[0];
    const int* src  = (const int*)d_in[1];
    const int* dst  = (const int*)d_in[2];
    const float* Wp[3][2] = {
        {(const float*)d_in[3], (const float*)d_in[4]},
        {(const float*)d_in[6], (const float*)d_in[7]},
        {(const float*)d_in[9], (const float*)d_in[10]},
    };
    const float* bp[3] = {(const float*)d_in[5], (const float*)d_in[8], (const float*)d_in[11]};
    float* out = (float*)d_out;

    char* base  = (char*)d_ws;
    int* cnt    = (int*)base;            // NN
    int* cursor = cnt + NN;              // NN
    int* rowptr = cursor + NN;           // NN+1 (padded to NN+4)
    int* eidx   = rowptr + (NN + 4);     // NE
    float* dinv = (float*)(eidx + NE);   // NN
    float* h0   = (float*)(base + (8u << 20));     // NN*F
    float* h1   = h0 + (size_t)NN * F;
    float* agg  = h1 + (size_t)NN * F;

    hipMemsetAsync(cnt, 0, sizeof(int) * 2 * NN, stream);  // cnt + cursor
    count_kernel<<<(NE + 255) / 256, 256, 0, stream>>>(dst, cnt);
    scan_kernel<<<1, 1024, 0, stream>>>(cnt, rowptr);
    deginv_kernel<<<(NN + 255) / 256, 256, 0, stream>>>(cnt, dinv);
    fill_kernel<<<(NE + 255) / 256, 256, 0, stream>>>(src, dst, rowptr, cursor, eidx);

    const int AGG_BLOCKS  = (NN * 64) / 256;   // 12500
    const int GEMM_BLOCKS = (NN + BM - 1) / BM; // 391

    for (int b = 0; b < NB; ++b) {
        const float* hin = x + (size_t)b * NN * F;
        float* hout = out + (size_t)b * NN * F;

        aggregate_kernel<<<AGG_BLOCKS, 256, 0, stream>>>(hin, rowptr, eidx, dinv, agg);
        sage_gemm<<<GEMM_BLOCKS, 256, 0, stream>>>(hin, agg, Wp[0][0], Wp[0][1], bp[0], h0);

        aggregate_kernel<<<AGG_BLOCKS, 256, 0, stream>>>(h0, rowptr, eidx, dinv, agg);
        sage_gemm<<<GEMM_BLOCKS, 256, 0, stream>>>(h0, agg, Wp[1][0], Wp[1][1], bp[1], h1);

        aggregate_kernel<<<AGG_BLOCKS, 256, 0, stream>>>(h1, rowptr, eidx, dinv, agg);
        sage_gemm<<<GEMM_BLOCKS, 256, 0, stream>>>(h1, agg, Wp[2][0], Wp[2][1], bp[2], hout);
    }
}

// Round 2
// 629.837 us; speedup vs baseline: 1.6575x; 1.6575x over previous
//
#include <hip/hip_runtime.h>

#define NN 50000
#define NE 800000
#define F  128
#define NB 2

typedef __attribute__((ext_vector_type(8))) short     bf16x8;
typedef __attribute__((ext_vector_type(4))) float     f32x4;
typedef __attribute__((ext_vector_type(8))) unsigned short u16x8;
typedef __attribute__((ext_vector_type(4))) unsigned short u16x4;

__device__ inline unsigned short f2bf_rn(float f) {
    unsigned u = __float_as_uint(f);
    u += 0x7FFFu + ((u >> 16) & 1u);
    return (unsigned short)(u >> 16);
}
__device__ inline float bf2f(unsigned short h) {
    return __uint_as_float(((unsigned)h) << 16);
}

// ---------------- CSR build ----------------

__global__ void count_kernel(const int* __restrict__ dst, int* __restrict__ cnt) {
    int e = blockIdx.x * blockDim.x + threadIdx.x;
    if (e < NE) atomicAdd(&cnt[dst[e]], 1);
}

__global__ void scan_kernel(const int* __restrict__ cnt, int* __restrict__ rowptr) {
    __shared__ int sd[1024];
    __shared__ int carry;
    if (threadIdx.x == 0) carry = 0;
    __syncthreads();
    for (int base = 0; base < NN; base += 1024) {
        int i = base + (int)threadIdx.x;
        int v = (i < NN) ? cnt[i] : 0;
        sd[threadIdx.x] = v;
        __syncthreads();
        for (int off = 1; off < 1024; off <<= 1) {
            int t = 0;
            if ((int)threadIdx.x >= off) t = sd[threadIdx.x - off];
            __syncthreads();
            sd[threadIdx.x] += t;
            __syncthreads();
        }
        if (i < NN) rowptr[i] = carry + sd[threadIdx.x] - v;  // exclusive
        __syncthreads();
        if (threadIdx.x == 0) carry += sd[1023];
        __syncthreads();
    }
    if (threadIdx.x == 0) rowptr[NN] = carry;
}

__global__ void deginv_kernel(const int* __restrict__ cnt, float* __restrict__ dinv) {
    int n = blockIdx.x * blockDim.x + threadIdx.x;
    if (n < NN) {
        int d = cnt[n];
        dinv[n] = (d > 0) ? 1.0f / (float)d : 0.0f;
    }
}

__global__ void fill_kernel(const int* __restrict__ src, const int* __restrict__ dst,
                            const int* __restrict__ rowptr, int* __restrict__ cursor,
                            int* __restrict__ eidx) {
    int e = blockIdx.x * blockDim.x + threadIdx.x;
    if (e < NE) {
        int d = dst[e];
        int p = rowptr[d] + atomicAdd(&cursor[d], 1);
        eidx[p] = src[e];
    }
}

// ---------------- weight split: Wcat[j][k] = k<128 ? Wself[j][k] : Wneigh[j][k-128]

__global__ void wsplit_kernel(const float* __restrict__ Ws, const float* __restrict__ Wn,
                              unsigned short* __restrict__ hi, unsigned short* __restrict__ lo) {
    int idx = blockIdx.x * blockDim.x + threadIdx.x;  // 128*256
    int j = idx >> 8, k = idx & 255;
    float v = (k < 128) ? Ws[j * 128 + k] : Wn[j * 128 + (k - 128)];
    unsigned short h = f2bf_rn(v);
    hi[idx] = h;
    lo[idx] = f2bf_rn(v - bf2f(h));
}

// ---------------- x split: fp32 -> hi/lo bf16 ----------------

__global__ void xsplit_kernel(const float* __restrict__ x,
                              unsigned short* __restrict__ hi, unsigned short* __restrict__ lo) {
    int idx = blockIdx.x * blockDim.x + threadIdx.x;  // NN*F/4 threads
    float4 v = *reinterpret_cast<const float4*>(&x[(size_t)idx * 4]);
    u16x4 h4, l4;
    float vv[4] = {v.x, v.y, v.z, v.w};
#pragma unroll
    for (int i = 0; i < 4; ++i) {
        unsigned short h = f2bf_rn(vv[i]);
        h4[i] = h;
        l4[i] = f2bf_rn(vv[i] - bf2f(h));
    }
    *reinterpret_cast<u16x4*>(&hi[(size_t)idx * 4]) = h4;
    *reinterpret_cast<u16x4*>(&lo[(size_t)idx * 4]) = l4;
}

// ---------------- mean aggregation: 1 wave/node, 4 edges/iter, unroll 2 ----------------

__global__ void aggregate_bf16(const unsigned short* __restrict__ h,
                               const int* __restrict__ rowptr, const int* __restrict__ eidx,
                               const float* __restrict__ dinv,
                               unsigned short* __restrict__ agg_hi, unsigned short* __restrict__ agg_lo) {
    int gtid = blockIdx.x * blockDim.x + threadIdx.x;
    int node = gtid >> 6;
    int lane = gtid & 63;
    if (node >= NN) return;
    int g = lane >> 4, li = lane & 15;
    int s0 = rowptr[node], s1 = rowptr[node + 1];

    float acc[8] = {0.f, 0.f, 0.f, 0.f, 0.f, 0.f, 0.f, 0.f};

    for (int e = s0; e < s1; e += 8) {
        int ea = e + g;
        int eb = e + 4 + g;
        int sa = (ea < s1) ? eidx[ea] : -1;
        int sb = (eb < s1) ? eidx[eb] : -1;
        u16x8 va, vb;
        if (sa >= 0) va = *reinterpret_cast<const u16x8*>(&h[(size_t)sa * F + li * 8]);
        if (sb >= 0) vb = *reinterpret_cast<const u16x8*>(&h[(size_t)sb * F + li * 8]);
        if (sa >= 0) {
#pragma unroll
            for (int i = 0; i < 8; ++i) acc[i] += bf2f(va[i]);
        }
        if (sb >= 0) {
#pragma unroll
            for (int i = 0; i < 8; ++i) acc[i] += bf2f(vb[i]);
        }
    }

#pragma unroll
    for (int i = 0; i < 8; ++i) {
        acc[i] += __shfl_xor(acc[i], 16);
        acc[i] += __shfl_xor(acc[i], 32);
    }

    if (g == 0) {
        float di = dinv[node];
        u16x8 h8, l8;
#pragma unroll
        for (int i = 0; i < 8; ++i) {
            float v = acc[i] * di;
            unsigned short hh = f2bf_rn(v);
            h8[i] = hh;
            l8[i] = f2bf_rn(v - bf2f(hh));
        }
        *reinterpret_cast<u16x8*>(&agg_hi[(size_t)node * F + li * 8]) = h8;
        *reinterpret_cast<u16x8*>(&agg_lo[(size_t)node * F + li * 8]) = l8;
    }
}

// ---------------- MFMA GEMM: out = relu([h|agg] @ Wcat^T + b), split bf16 hi/lo ----------------
// Block: 128 M-rows, 128 N-cols, 4 waves in 2x2; wave = 64x64 (4x4 frags of 16x16x32).

__global__ __launch_bounds__(256) void sage_gemm_mfma(
    const unsigned short* __restrict__ Shi, const unsigned short* __restrict__ Slo,
    const unsigned short* __restrict__ Ghi, const unsigned short* __restrict__ Glo,
    const unsigned short* __restrict__ Whi, const unsigned short* __restrict__ Wlo,
    const float* __restrict__ bias,
    float* __restrict__ outf, unsigned short* __restrict__ ohi, unsigned short* __restrict__ olo,
    int final_layer)
{
    int tid = threadIdx.x;
    int lane = tid & 63, wave = tid >> 6;
    int wm = wave >> 1, wn = wave & 1;
    int l15 = lane & 15, kg = lane >> 4;
    int row_base = blockIdx.x * 128 + wm * 64;
    int col_base = wn * 64;

    f32x4 acc[4][4];
#pragma unroll
    for (int m = 0; m < 4; ++m)
#pragma unroll
        for (int n = 0; n < 4; ++n) acc[m][n] = (f32x4){0.f, 0.f, 0.f, 0.f};

    int arow[4];
#pragma unroll
    for (int m = 0; m < 4; ++m) arow[m] = min(row_base + m * 16 + l15, NN - 1);
    int bcol[4];
    float bv[4];
#pragma unroll
    for (int n = 0; n < 4; ++n) {
        bcol[n] = col_base + n * 16 + l15;
        bv[n] = bias[bcol[n]];
    }

#pragma unroll
    for (int ks = 0; ks < 8; ++ks) {
        const unsigned short* Ahi = (ks < 4) ? Shi : Ghi;
        const unsigned short* Alo = (ks < 4) ? Slo : Glo;
        int ka = (ks & 3) * 32 + kg * 8;
        int kb = ks * 32 + kg * 8;

        bf16x8 ah[4], al[4], bh[4], bl[4];
#pragma unroll
        for (int m = 0; m < 4; ++m) {
            size_t off = (size_t)arow[m] * F + ka;
            ah[m] = *reinterpret_cast<const bf16x8*>(&Ahi[off]);
            al[m] = *reinterpret_cast<const bf16x8*>(&Alo[off]);
        }
#pragma unroll
        for (int n = 0; n < 4; ++n) {
            size_t off = (size_t)bcol[n] * 256 + kb;
            bh[n] = *reinterpret_cast<const bf16x8*>(&Whi[off]);
            bl[n] = *reinterpret_cast<const bf16x8*>(&Wlo[off]);
        }

#pragma unroll
        for (int m = 0; m < 4; ++m)
#pragma unroll
            for (int n = 0; n < 4; ++n) {
                acc[m][n] = __builtin_amdgcn_mfma_f32_16x16x32_bf16(ah[m], bh[n], acc[m][n], 0, 0, 0);
                acc[m][n] = __builtin_amdgcn_mfma_f32_16x16x32_bf16(ah[m], bl[n], acc[m][n], 0, 0, 0);
                acc[m][n] = __builtin_amdgcn_mfma_f32_16x16x32_bf16(al[m], bh[n], acc[m][n], 0, 0, 0);
            }
    }

    // epilogue: C frag layout col=lane&15, row=(lane>>4)*4+i
#pragma unroll
    for (int m = 0; m < 4; ++m) {
#pragma unroll
        for (int i = 0; i < 4; ++i) {
            int r = row_base + m * 16 + kg * 4 + i;
            if (r < NN) {
#pragma unroll
                for (int n = 0; n < 4; ++n) {
                    float v = acc[m][n][i] + bv[n];
                    v = fmaxf(v, 0.f);
                    size_t off = (size_t)r * F + bcol[n];
                    if (final_layer) {
                        outf[off] = v;
                    } else {
                        unsigned short hh = f2bf_rn(v);
                        ohi[off] = hh;
                        olo[off] = f2bf_rn(v - bf2f(hh));
                    }
                }
            }
        }
    }
}

// ---------------- launcher ----------------

extern "C" void kernel_launch(void* const* d_in, const int* in_sizes, int n_in,
                              void* d_out, int out_size, void* d_ws, size_t ws_size,
                              hipStream_t stream) {
    const float* x  = (const float*)d_in[0];
    const int* src  = (const int*)d_in[1];
    const int* dst  = (const int*)d_in[2];
    const float* Wp[3][2] = {
        {(const float*)d_in[3], (const float*)d_in[4]},
        {(const float*)d_in[6], (const float*)d_in[7]},
        {(const float*)d_in[9], (const float*)d_in[10]},
    };
    const float* bp[3] = {(const float*)d_in[5], (const float*)d_in[8], (const float*)d_in[11]};
    float* out = (float*)d_out;

    char* p = (char*)d_ws;
    auto alloc = [&](size_t b) -> void* {
        void* r = (void*)p;
        p += (b + 255) & ~(size_t)255;
        return r;
    };
    int* cnt    = (int*)alloc(sizeof(int) * NN);
    int* cursor = (int*)alloc(sizeof(int) * NN);
    int* rowptr = (int*)alloc(sizeof(int) * (NN + 1));
    int* eidx   = (int*)alloc(sizeof(int) * NE);
    float* dinv = (float*)alloc(sizeof(float) * NN);
    unsigned short* Whi = (unsigned short*)alloc(sizeof(short) * 3 * 128 * 256);
    unsigned short* Wlo = (unsigned short*)alloc(sizeof(short) * 3 * 128 * 256);
    unsigned short* Ahi = (unsigned short*)alloc(sizeof(short) * NN * F);
    unsigned short* Alo = (unsigned short*)alloc(sizeof(short) * NN * F);
    unsigned short* Bhi = (unsigned short*)alloc(sizeof(short) * NN * F);
    unsigned short* Blo = (unsigned short*)alloc(sizeof(short) * NN * F);
    unsigned short* Ghi = (unsigned short*)alloc(sizeof(short) * NN * F);
    unsigned short* Glo = (unsigned short*)alloc(sizeof(short) * NN * F);

    hipMemsetAsync(cnt, 0, sizeof(int) * NN, stream);
    hipMemsetAsync(cursor, 0, sizeof(int) * NN, stream);
    count_kernel<<<(NE + 255) / 256, 256, 0, stream>>>(dst, cnt);
    scan_kernel<<<1, 1024, 0, stream>>>(cnt, rowptr);
    deginv_kernel<<<(NN + 255) / 256, 256, 0, stream>>>(cnt, dinv);
    fill_kernel<<<(NE + 255) / 256, 256, 0, stream>>>(src, dst, rowptr, cursor, eidx);

    for (int l = 0; l < 3; ++l)
        wsplit_kernel<<<128, 256, 0, stream>>>(Wp[l][0], Wp[l][1], Whi + l * 32768, Wlo + l * 32768);

    const int AGG_BLOCKS  = (NN * 64) / 256;       // 12500
    const int GEMM_BLOCKS = (NN + 127) / 128;      // 391
    const int XS_BLOCKS   = (NN * F / 4) / 256;    // 6250

    for (int b = 0; b < NB; ++b) {
        const float* xb = x + (size_t)b * NN * F;
        float* outb = out + (size_t)b * NN * F;

        xsplit_kernel<<<XS_BLOCKS, 256, 0, stream>>>(xb, Ahi, Alo);

        aggregate_bf16<<<AGG_BLOCKS, 256, 0, stream>>>(Ahi, rowptr, eidx, dinv, Ghi, Glo);
        sage_gemm_mfma<<<GEMM_BLOCKS, 256, 0, stream>>>(Ahi, Alo, Ghi, Glo,
                                                        Whi + 0 * 32768, Wlo + 0 * 32768, bp[0],
                                                        nullptr, Bhi, Blo, 0);

        aggregate_bf16<<<AGG_BLOCKS, 256, 0, stream>>>(Bhi, rowptr, eidx, dinv, Ghi, Glo);
        sage_gemm_mfma<<<GEMM_BLOCKS, 256, 0, stream>>>(Bhi, Blo, Ghi, Glo,
                                                        Whi + 1 * 32768, Wlo + 1 * 32768, bp[1],
                                                        nullptr, Ahi, Alo, 0);

        aggregate_bf16<<<AGG_BLOCKS, 256, 0, stream>>>(Ahi, rowptr, eidx, dinv, Ghi, Glo);
        sage_gemm_mfma<<<GEMM_BLOCKS, 256, 0, stream>>>(Ahi, Alo, Ghi, Glo,
                                                        Whi + 2 * 32768, Wlo + 2 * 32768, bp[2],
                                                        outb, nullptr, nullptr, 1);
    }
}

// Round 3
// 546.886 us; speedup vs baseline: 1.9089x; 1.1517x over previous
//
#include <hip/hip_runtime.h>

#define NN 50000
#define NE 800000
#define F  128
#define NB 2

typedef __attribute__((ext_vector_type(8))) short     bf16x8;
typedef __attribute__((ext_vector_type(4))) float     f32x4;
typedef __attribute__((ext_vector_type(8))) unsigned short u16x8;
typedef __attribute__((ext_vector_type(4))) unsigned short u16x4;

__device__ inline unsigned short f2bf_rn(float f) {
    unsigned u = __float_as_uint(f);
    u += 0x7FFFu + ((u >> 16) & 1u);
    return (unsigned short)(u >> 16);
}
__device__ inline float bf2f(unsigned short h) {
    return __uint_as_float(((unsigned)h) << 16);
}

// ---------------- CSR build ----------------

__global__ void count_kernel(const int* __restrict__ dst, int* __restrict__ cnt) {
    int e = blockIdx.x * blockDim.x + threadIdx.x;
    if (e < NE) atomicAdd(&cnt[dst[e]], 1);
}

// level 1: block-local exclusive scan over 1024 elements + block sum
__global__ __launch_bounds__(1024) void scan1_kernel(const int* __restrict__ cnt,
                                                     int* __restrict__ local_ex,
                                                     int* __restrict__ blocksums) {
    __shared__ int sd[1024];
    int i = blockIdx.x * 1024 + threadIdx.x;
    int v = (i < NN) ? cnt[i] : 0;
    sd[threadIdx.x] = v;
    __syncthreads();
    for (int off = 1; off < 1024; off <<= 1) {
        int t = 0;
        if ((int)threadIdx.x >= off) t = sd[threadIdx.x - off];
        __syncthreads();
        sd[threadIdx.x] += t;
        __syncthreads();
    }
    if (i < NN) local_ex[i] = sd[threadIdx.x] - v;  // exclusive within block
    if (threadIdx.x == 1023) blocksums[blockIdx.x] = sd[1023];
}

// level 2: one wave exclusive-scans the 49 block sums in place
__global__ void scan2_kernel(int* __restrict__ bs, int nb) {
    int lane = threadIdx.x;
    int v = (lane < nb) ? bs[lane] : 0;
    for (int off = 1; off < 64; off <<= 1) {
        int t = __shfl_up(v, off);
        if (lane >= off) v += t;
    }
    int ex = __shfl_up(v, 1);
    if (lane == 0) ex = 0;
    if (lane < nb) bs[lane] = ex;
}

// level 3: combine + deg_inv fused
__global__ void scan3_kernel(const int* __restrict__ local_ex, const int* __restrict__ bs,
                             const int* __restrict__ cnt,
                             int* __restrict__ rowptr, float* __restrict__ dinv) {
    int i = blockIdx.x * blockDim.x + threadIdx.x;
    if (i < NN) {
        rowptr[i] = local_ex[i] + bs[i >> 10];
        int d = cnt[i];
        dinv[i] = (d > 0) ? 1.0f / (float)d : 0.0f;
    }
    if (i == 0) rowptr[NN] = NE;
}

__global__ void fill_kernel(const int* __restrict__ src, const int* __restrict__ dst,
                            const int* __restrict__ rowptr, int* __restrict__ cursor,
                            int* __restrict__ eidx) {
    int e = blockIdx.x * blockDim.x + threadIdx.x;
    if (e < NE) {
        int d = dst[e];
        int p = rowptr[d] + atomicAdd(&cursor[d], 1);
        eidx[p] = src[e];
    }
}

// ---------------- weight split: all 3 layers in one launch ----------------
// Wcat[l][j][k] = k<128 ? Wself_l[j][k] : Wneigh_l[j][k-128]

__global__ void wsplit_kernel(const float* __restrict__ Ws0, const float* __restrict__ Wn0,
                              const float* __restrict__ Ws1, const float* __restrict__ Wn1,
                              const float* __restrict__ Ws2, const float* __restrict__ Wn2,
                              unsigned short* __restrict__ hi, unsigned short* __restrict__ lo) {
    int idx = blockIdx.x * blockDim.x + threadIdx.x;  // 3*128*256
    int l = idx >> 15;
    int r = idx & 32767;
    int j = r >> 8, k = r & 255;
    const float* Ws = (l == 0) ? Ws0 : (l == 1) ? Ws1 : Ws2;
    const float* Wn = (l == 0) ? Wn0 : (l == 1) ? Wn1 : Wn2;
    float v = (k < 128) ? Ws[j * 128 + k] : Wn[j * 128 + (k - 128)];
    unsigned short h = f2bf_rn(v);
    hi[idx] = h;
    lo[idx] = f2bf_rn(v - bf2f(h));
}

// ---------------- x split: fp32 -> hi/lo bf16 (both batches) ----------------

__global__ void xsplit_kernel(const float* __restrict__ x,
                              unsigned short* __restrict__ hi, unsigned short* __restrict__ lo) {
    size_t idx = (size_t)blockIdx.x * blockDim.x + threadIdx.x;  // NB*NN*F/4 threads
    float4 v = *reinterpret_cast<const float4*>(&x[idx * 4]);
    u16x4 h4, l4;
    float vv[4] = {v.x, v.y, v.z, v.w};
#pragma unroll
    for (int i = 0; i < 4; ++i) {
        unsigned short h = f2bf_rn(vv[i]);
        h4[i] = h;
        l4[i] = f2bf_rn(vv[i] - bf2f(h));
    }
    *reinterpret_cast<u16x4*>(&hi[idx * 4]) = h4;
    *reinterpret_cast<u16x4*>(&lo[idx * 4]) = l4;
}

// ---------------- mean aggregation: 1 wave/node, 4 edges/iter, unroll 2 ----------------

__global__ void aggregate_bf16(const unsigned short* __restrict__ h,
                               const int* __restrict__ rowptr, const int* __restrict__ eidx,
                               const float* __restrict__ dinv,
                               unsigned short* __restrict__ agg_hi, unsigned short* __restrict__ agg_lo) {
    int gtid = blockIdx.x * blockDim.x + threadIdx.x;
    int node = gtid >> 6;
    int lane = gtid & 63;
    if (node >= NN) return;
    int g = lane >> 4, li = lane & 15;
    int s0 = rowptr[node], s1 = rowptr[node + 1];

    float acc[8] = {0.f, 0.f, 0.f, 0.f, 0.f, 0.f, 0.f, 0.f};

    for (int e = s0; e < s1; e += 8) {
        int ea = e + g;
        int eb = e + 4 + g;
        int sa = (ea < s1) ? eidx[ea] : -1;
        int sb = (eb < s1) ? eidx[eb] : -1;
        u16x8 va, vb;
        if (sa >= 0) va = *reinterpret_cast<const u16x8*>(&h[(size_t)sa * F + li * 8]);
        if (sb >= 0) vb = *reinterpret_cast<const u16x8*>(&h[(size_t)sb * F + li * 8]);
        if (sa >= 0) {
#pragma unroll
            for (int i = 0; i < 8; ++i) acc[i] += bf2f(va[i]);
        }
        if (sb >= 0) {
#pragma unroll
            for (int i = 0; i < 8; ++i) acc[i] += bf2f(vb[i]);
        }
    }

#pragma unroll
    for (int i = 0; i < 8; ++i) {
        acc[i] += __shfl_xor(acc[i], 16);
        acc[i] += __shfl_xor(acc[i], 32);
    }

    if (g == 0) {
        float di = dinv[node];
        u16x8 h8, l8;
#pragma unroll
        for (int i = 0; i < 8; ++i) {
            float v = acc[i] * di;
            unsigned short hh = f2bf_rn(v);
            h8[i] = hh;
            l8[i] = f2bf_rn(v - bf2f(hh));
        }
        *reinterpret_cast<u16x8*>(&agg_hi[(size_t)node * F + li * 8]) = h8;
        *reinterpret_cast<u16x8*>(&agg_lo[(size_t)node * F + li * 8]) = l8;
    }
}

// ---------------- MFMA GEMM: out = relu([h|agg] @ Wcat^T + b), split bf16 hi/lo ----------------
// Block: 128 M-rows, 128 N-cols, 4 waves in 2x2; wave = 64x64 (4x4 frags of 16x16x32).

__global__ __launch_bounds__(256) void sage_gemm_mfma(
    const unsigned short* __restrict__ Shi, const unsigned short* __restrict__ Slo,
    const unsigned short* __restrict__ Ghi, const unsigned short* __restrict__ Glo,
    const unsigned short* __restrict__ Whi, const unsigned short* __restrict__ Wlo,
    const float* __restrict__ bias,
    float* __restrict__ outf, unsigned short* __restrict__ ohi, unsigned short* __restrict__ olo,
    int final_layer)
{
    int tid = threadIdx.x;
    int lane = tid & 63, wave = tid >> 6;
    int wm = wave >> 1, wn = wave & 1;
    int l15 = lane & 15, kg = lane >> 4;
    int row_base = blockIdx.x * 128 + wm * 64;
    int col_base = wn * 64;

    f32x4 acc[4][4];
#pragma unroll
    for (int m = 0; m < 4; ++m)
#pragma unroll
        for (int n = 0; n < 4; ++n) acc[m][n] = (f32x4){0.f, 0.f, 0.f, 0.f};

    int arow[4];
#pragma unroll
    for (int m = 0; m < 4; ++m) arow[m] = min(row_base + m * 16 + l15, NN - 1);
    int bcol[4];
    float bv[4];
#pragma unroll
    for (int n = 0; n < 4; ++n) {
        bcol[n] = col_base + n * 16 + l15;
        bv[n] = bias[bcol[n]];
    }

#pragma unroll
    for (int ks = 0; ks < 8; ++ks) {
        const unsigned short* Ahi = (ks < 4) ? Shi : Ghi;
        const unsigned short* Alo = (ks < 4) ? Slo : Glo;
        int ka = (ks & 3) * 32 + kg * 8;
        int kb = ks * 32 + kg * 8;

        bf16x8 ah[4], al[4], bh[4], bl[4];
#pragma unroll
        for (int m = 0; m < 4; ++m) {
            size_t off = (size_t)arow[m] * F + ka;
            ah[m] = *reinterpret_cast<const bf16x8*>(&Ahi[off]);
            al[m] = *reinterpret_cast<const bf16x8*>(&Alo[off]);
        }
#pragma unroll
        for (int n = 0; n < 4; ++n) {
            size_t off = (size_t)bcol[n] * 256 + kb;
            bh[n] = *reinterpret_cast<const bf16x8*>(&Whi[off]);
            bl[n] = *reinterpret_cast<const bf16x8*>(&Wlo[off]);
        }

#pragma unroll
        for (int m = 0; m < 4; ++m)
#pragma unroll
            for (int n = 0; n < 4; ++n) {
                acc[m][n] = __builtin_amdgcn_mfma_f32_16x16x32_bf16(ah[m], bh[n], acc[m][n], 0, 0, 0);
                acc[m][n] = __builtin_amdgcn_mfma_f32_16x16x32_bf16(ah[m], bl[n], acc[m][n], 0, 0, 0);
                acc[m][n] = __builtin_amdgcn_mfma_f32_16x16x32_bf16(al[m], bh[n], acc[m][n], 0, 0, 0);
            }
    }

    // epilogue: C frag layout col=lane&15, row=(lane>>4)*4+i
#pragma unroll
    for (int m = 0; m < 4; ++m) {
#pragma unroll
        for (int i = 0; i < 4; ++i) {
            int r = row_base + m * 16 + kg * 4 + i;
            if (r < NN) {
#pragma unroll
                for (int n = 0; n < 4; ++n) {
                    float v = acc[m][n][i] + bv[n];
                    v = fmaxf(v, 0.f);
                    size_t off = (size_t)r * F + bcol[n];
                    if (final_layer) {
                        outf[off] = v;
                    } else {
                        unsigned short hh = f2bf_rn(v);
                        ohi[off] = hh;
                        olo[off] = f2bf_rn(v - bf2f(hh));
                    }
                }
            }
        }
    }
}

// ---------------- launcher ----------------

extern "C" void kernel_launch(void* const* d_in, const int* in_sizes, int n_in,
                              void* d_out, int out_size, void* d_ws, size_t ws_size,
                              hipStream_t stream) {
    const float* x  = (const float*)d_in[0];
    const int* src  = (const int*)d_in[1];
    const int* dst  = (const int*)d_in[2];
    const float* Wp[3][2] = {
        {(const float*)d_in[3], (const float*)d_in[4]},
        {(const float*)d_in[6], (const float*)d_in[7]},
        {(const float*)d_in[9], (const float*)d_in[10]},
    };
    const float* bp[3] = {(const float*)d_in[5], (const float*)d_in[8], (const float*)d_in[11]};
    float* out = (float*)d_out;

    char* p = (char*)d_ws;
    auto alloc = [&](size_t b) -> void* {
        void* r = (void*)p;
        p += (b + 255) & ~(size_t)255;
        return r;
    };
    int* cnt      = (int*)alloc(sizeof(int) * NN);
    int* cursor   = (int*)alloc(sizeof(int) * NN);
    int* rowptr   = (int*)alloc(sizeof(int) * (NN + 1));
    int* local_ex = (int*)alloc(sizeof(int) * NN);
    int* bsums    = (int*)alloc(sizeof(int) * 64);
    int* eidx     = (int*)alloc(sizeof(int) * NE);
    float* dinv   = (float*)alloc(sizeof(float) * NN);
    unsigned short* Whi = (unsigned short*)alloc(sizeof(short) * 3 * 128 * 256);
    unsigned short* Wlo = (unsigned short*)alloc(sizeof(short) * 3 * 128 * 256);
    // per-batch hi/lo feature buffers (A = layer io, B = layer io, G = agg)
    unsigned short* Ahi[NB], *Alo[NB], *Bhi[NB], *Blo[NB];
    for (int b = 0; b < NB; ++b) {
        Ahi[b] = (unsigned short*)alloc(sizeof(short) * NN * F);
        Alo[b] = (unsigned short*)alloc(sizeof(short) * NN * F);
        Bhi[b] = (unsigned short*)alloc(sizeof(short) * NN * F);
        Blo[b] = (unsigned short*)alloc(sizeof(short) * NN * F);
    }
    unsigned short* Ghi = (unsigned short*)alloc(sizeof(short) * NN * F);
    unsigned short* Glo = (unsigned short*)alloc(sizeof(short) * NN * F);

    hipMemsetAsync(cnt, 0, (char*)rowptr - (char*)cnt, stream);  // cnt + cursor

    count_kernel<<<(NE + 255) / 256, 256, 0, stream>>>(dst, cnt);
    const int NSB = (NN + 1023) / 1024;  // 49
    scan1_kernel<<<NSB, 1024, 0, stream>>>(cnt, local_ex, bsums);
    scan2_kernel<<<1, 64, 0, stream>>>(bsums, NSB);
    scan3_kernel<<<(NN + 255) / 256, 256, 0, stream>>>(local_ex, bsums, cnt, rowptr, dinv);
    fill_kernel<<<(NE + 255) / 256, 256, 0, stream>>>(src, dst, rowptr, cursor, eidx);

    wsplit_kernel<<<3 * 128, 256, 0, stream>>>(Wp[0][0], Wp[0][1], Wp[1][0], Wp[1][1],
                                               Wp[2][0], Wp[2][1], Whi, Wlo);

    const int AGG_BLOCKS  = (NN * 64) / 256;            // 12500
    const int GEMM_BLOCKS = (NN + 127) / 128;           // 391
    const int XS_BLOCKS   = ((size_t)NB * NN * F / 4) / 256;  // 12500

    // x split for both batches in one launch (Ahi/Alo are contiguous per batch? no —
    // they interleave with B buffers, so launch per batch at the right base)
    for (int b = 0; b < NB; ++b) {
        xsplit_kernel<<<XS_BLOCKS / NB, 256, 0, stream>>>(x + (size_t)b * NN * F, Ahi[b], Alo[b]);
    }

    for (int b = 0; b < NB; ++b) {
        float* outb = out + (size_t)b * NN * F;

        aggregate_bf16<<<AGG_BLOCKS, 256, 0, stream>>>(Ahi[b], rowptr, eidx, dinv, Ghi, Glo);
        sage_gemm_mfma<<<GEMM_BLOCKS, 256, 0, stream>>>(Ahi[b], Alo[b], Ghi, Glo,
                                                        Whi + 0 * 32768, Wlo + 0 * 32768, bp[0],
                                                        nullptr, Bhi[b], Blo[b], 0);

        aggregate_bf16<<<AGG_BLOCKS, 256, 0, stream>>>(Bhi[b], rowptr, eidx, dinv, Ghi, Glo);
        sage_gemm_mfma<<<GEMM_BLOCKS, 256, 0, stream>>>(Bhi[b], Blo[b], Ghi, Glo,
                                                        Whi + 1 * 32768, Wlo + 1 * 32768, bp[1],
                                                        nullptr, Ahi[b], Alo[b], 0);

        aggregate_bf16<<<AGG_BLOCKS, 256, 0, stream>>>(Ahi[b], rowptr, eidx, dinv, Ghi, Glo);
        sage_gemm_mfma<<<GEMM_BLOCKS, 256, 0, stream>>>(Ahi[b], Alo[b], Ghi, Glo,
                                                        Whi + 2 * 32768, Wlo + 2 * 32768, bp[2],
                                                        outb, nullptr, nullptr, 1);
    }
}